// Round 3
// baseline (1749.872 us; speedup 1.0000x reference)
//
#include <hip/hip_runtime.h>
#include <hip/hip_bf16.h>
#include <stdint.h>

#define CIN  16
#define COUT 32
#define K2   9

// native clang vector types — required by __builtin_nontemporal_*
typedef float    nfloat4 __attribute__((ext_vector_type(4)));
typedef uint32_t nuint4  __attribute__((ext_vector_type(4)));

// ---------- bf16 helpers (RNE) ----------
__device__ __forceinline__ uint16_t f2bf(float f) {
    union { float f; uint32_t u; } a; a.f = f;
    uint32_t u = a.u;
    uint32_t r = u + 0x7FFFu + ((u >> 16) & 1u);
    return (uint16_t)(r >> 16);
}
__device__ __forceinline__ float bf2f(uint32_t bits16) {
    union { uint32_t u; float f; } a; a.u = bits16 << 16; return a.f;
}

// ---------- mask-width detection (k=4 center row is all-true) ----------
__global__ void detect_mask_kernel(const uint32_t* __restrict__ mw,
                                   int* __restrict__ flag, int n) {
    int t = threadIdx.x;
    uint32_t w = mw[(size_t)4 * (size_t)n + (size_t)t];
    unsigned long long b = __ballot(w == 1u);
    if (t == 0) *flag = (b == ~0ull) ? 1 : 0;
}

// ---------- x fp32 -> bf16 staging (keeps conv1 gather footprint at 64 MB) ----------
__global__ void __launch_bounds__(256)
xcast_kernel(const float* __restrict__ x, uint16_t* __restrict__ xbf, long total8) {
    long t = (long)blockIdx.x * blockDim.x + threadIdx.x;
    if (t >= total8) return;
    const nfloat4* xp = (const nfloat4*)(x + t * 8);
    nfloat4 a = __builtin_nontemporal_load(xp);
    nfloat4 b = __builtin_nontemporal_load(xp + 1);
    nuint4 w;
    w.x = (uint32_t)f2bf(a.x) | ((uint32_t)f2bf(a.y) << 16);
    w.y = (uint32_t)f2bf(a.z) | ((uint32_t)f2bf(a.w) << 16);
    w.z = (uint32_t)f2bf(b.x) | ((uint32_t)f2bf(b.y) << 16);
    w.w = (uint32_t)f2bf(b.z) | ((uint32_t)f2bf(b.w) << 16);
    ((nuint4*)(xbf + t * 8))[0] = w;   // regular store: xbf should live in L3
}

// ---------- conv1 + relu -> h (bf16) ----------
template <int XBF>
__global__ void __launch_bounds__(256)
conv1_kernel(const void*  __restrict__ xsrc,
             const float* __restrict__ W1,
             const float* __restrict__ b1,
             const int*   __restrict__ nidx,
             const void*  __restrict__ nmask,
             const int*   __restrict__ mflag,
             uint16_t*    __restrict__ hbuf,
             int n)
{
    const int i = blockIdx.x * blockDim.x + threadIdx.x;
    if (i >= n) return;
    const int mode32 = *mflag;
    const int*     m32 = (const int*)nmask;
    const uint8_t* m8  = (const uint8_t*)nmask;

    float acc[COUT];
    #pragma unroll
    for (int o = 0; o < COUT; ++o) acc[o] = b1[o];

    #pragma unroll
    for (int k = 0; k < K2; ++k) {
        const size_t e = (size_t)k * (size_t)n + (size_t)i;
        const int id = __builtin_nontemporal_load(nidx + e);
        const bool mv = mode32 ? (__builtin_nontemporal_load(m32 + e) != 0)
                               : (__builtin_nontemporal_load(m8  + e) != 0);
        if (mv) {
            float xv[CIN];
            if (XBF) {
                const nuint4* xr = (const nuint4*)((const uint16_t*)xsrc + (size_t)id * CIN);
                nuint4 a = xr[0], b = xr[1];
                xv[0]  = bf2f(a.x & 0xFFFFu); xv[1]  = bf2f(a.x >> 16);
                xv[2]  = bf2f(a.y & 0xFFFFu); xv[3]  = bf2f(a.y >> 16);
                xv[4]  = bf2f(a.z & 0xFFFFu); xv[5]  = bf2f(a.z >> 16);
                xv[6]  = bf2f(a.w & 0xFFFFu); xv[7]  = bf2f(a.w >> 16);
                xv[8]  = bf2f(b.x & 0xFFFFu); xv[9]  = bf2f(b.x >> 16);
                xv[10] = bf2f(b.y & 0xFFFFu); xv[11] = bf2f(b.y >> 16);
                xv[12] = bf2f(b.z & 0xFFFFu); xv[13] = bf2f(b.z >> 16);
                xv[14] = bf2f(b.w & 0xFFFFu); xv[15] = bf2f(b.w >> 16);
            } else {
                const nfloat4* xr = (const nfloat4*)((const float*)xsrc + (size_t)id * CIN);
                #pragma unroll
                for (int q = 0; q < 4; ++q) {
                    nfloat4 a = xr[q];
                    xv[4*q+0] = a.x; xv[4*q+1] = a.y; xv[4*q+2] = a.z; xv[4*q+3] = a.w;
                }
            }
            const float* Wk = W1 + k * (CIN * COUT);
            #pragma unroll
            for (int c = 0; c < CIN; ++c) {
                const float xc = xv[c];
                #pragma unroll
                for (int o = 0; o < COUT; ++o)
                    acc[o] = fmaf(xc, Wk[c * COUT + o], acc[o]);
            }
        }
    }

    // relu + bf16 pack; regular stores (h must stay in L2/L3 for conv2's gathers)
    nuint4* hq = (nuint4*)(hbuf + (size_t)i * COUT);
    #pragma unroll
    for (int j = 0; j < 4; ++j) {
        nuint4 w;
        w.x = (uint32_t)f2bf(fmaxf(acc[8*j+0], 0.f)) | ((uint32_t)f2bf(fmaxf(acc[8*j+1], 0.f)) << 16);
        w.y = (uint32_t)f2bf(fmaxf(acc[8*j+2], 0.f)) | ((uint32_t)f2bf(fmaxf(acc[8*j+3], 0.f)) << 16);
        w.z = (uint32_t)f2bf(fmaxf(acc[8*j+4], 0.f)) | ((uint32_t)f2bf(fmaxf(acc[8*j+5], 0.f)) << 16);
        w.w = (uint32_t)f2bf(fmaxf(acc[8*j+6], 0.f)) | ((uint32_t)f2bf(fmaxf(acc[8*j+7], 0.f)) << 16);
        hq[j] = w;
    }
}

// ---------- conv2 + residual proj + relu -> out ----------
__global__ void __launch_bounds__(256)
conv2_kernel(const float*    __restrict__ x,
             const float*    __restrict__ W2,
             const float*    __restrict__ b2,
             const float*    __restrict__ Wp,
             const float*    __restrict__ bp,
             const int*      __restrict__ nidx,
             const void*     __restrict__ nmask,
             const int*      __restrict__ mflag,
             const uint16_t* __restrict__ hbuf,
             float*          __restrict__ out,
             int n)
{
    const int i = blockIdx.x * blockDim.x + threadIdx.x;
    if (i >= n) return;
    const int mode32 = *mflag;
    const int*     m32 = (const int*)nmask;
    const uint8_t* m8  = (const uint8_t*)nmask;

    float acc[COUT];
    #pragma unroll
    for (int o = 0; o < COUT; ++o) acc[o] = b2[o] + bp[o];

    // residual 1x1: x[i] @ Wp — streamed once, keep out of L3 (NT loads)
    {
        const nfloat4* xr = (const nfloat4*)(x + (size_t)i * CIN);
        float xv[CIN];
        #pragma unroll
        for (int q = 0; q < 4; ++q) {
            nfloat4 a = __builtin_nontemporal_load(xr + q);
            xv[4*q+0] = a.x; xv[4*q+1] = a.y; xv[4*q+2] = a.z; xv[4*q+3] = a.w;
        }
        #pragma unroll
        for (int c = 0; c < CIN; ++c) {
            const float xc = xv[c];
            #pragma unroll
            for (int o = 0; o < COUT; ++o)
                acc[o] = fmaf(xc, Wp[c * COUT + o], acc[o]);
        }
    }

    #pragma unroll
    for (int k = 0; k < K2; ++k) {
        const size_t e = (size_t)k * (size_t)n + (size_t)i;
        const int id = __builtin_nontemporal_load(nidx + e);
        const bool mv = mode32 ? (__builtin_nontemporal_load(m32 + e) != 0)
                               : (__builtin_nontemporal_load(m8  + e) != 0);
        if (mv) {
            // h-row gather: 64 B bf16 — the ONE thing we want hitting L3
            const nuint4* hr = (const nuint4*)(hbuf + (size_t)id * COUT);
            float hv[COUT];
            #pragma unroll
            for (int j = 0; j < 4; ++j) {
                nuint4 w = hr[j];
                hv[8*j+0] = bf2f(w.x & 0xFFFFu); hv[8*j+1] = bf2f(w.x >> 16);
                hv[8*j+2] = bf2f(w.y & 0xFFFFu); hv[8*j+3] = bf2f(w.y >> 16);
                hv[8*j+4] = bf2f(w.z & 0xFFFFu); hv[8*j+5] = bf2f(w.z >> 16);
                hv[8*j+6] = bf2f(w.w & 0xFFFFu); hv[8*j+7] = bf2f(w.w >> 16);
            }
            const float* Wk = W2 + k * (COUT * COUT);
            #pragma unroll
            for (int c = 0; c < COUT; ++c) {
                const float hc = hv[c];
                #pragma unroll
                for (int o = 0; o < COUT; ++o)
                    acc[o] = fmaf(hc, Wk[c * COUT + o], acc[o]);
            }
        }
    }

    // out: 256 MB, never re-read — non-temporal stores keep L3 for h
    nfloat4* oq = (nfloat4*)(out + (size_t)i * COUT);
    #pragma unroll
    for (int j = 0; j < 8; ++j) {
        nfloat4 v;
        v.x = fmaxf(acc[4*j+0], 0.0f); v.y = fmaxf(acc[4*j+1], 0.0f);
        v.z = fmaxf(acc[4*j+2], 0.0f); v.w = fmaxf(acc[4*j+3], 0.0f);
        __builtin_nontemporal_store(v, oq + j);
    }
}

extern "C" void kernel_launch(void* const* d_in, const int* in_sizes, int n_in,
                              void* d_out, int out_size, void* d_ws, size_t ws_size,
                              hipStream_t stream) {
    const float* x    = (const float*)d_in[0];
    const float* W1   = (const float*)d_in[1];
    const float* b1   = (const float*)d_in[2];
    const float* W2   = (const float*)d_in[3];
    const float* b2   = (const float*)d_in[4];
    const float* Wp   = (const float*)d_in[5];
    const float* bp   = (const float*)d_in[6];
    const int*   nidx = (const int*)d_in[7];
    const void*  nmask = d_in[8];
    const int n = in_sizes[0] / CIN;

    int*      mflag = (int*)d_ws;
    uint16_t* hbuf  = (uint16_t*)((char*)d_ws + 256);               // 128 MB bf16 h
    const size_t h_bytes  = (size_t)n * COUT * sizeof(uint16_t);
    uint16_t* xbf   = (uint16_t*)((char*)d_ws + 256 + h_bytes);     // 64 MB bf16 x
    const size_t need_xbf = 256 + h_bytes + (size_t)n * CIN * sizeof(uint16_t);
    const bool use_xbf = (ws_size >= need_xbf);

    detect_mask_kernel<<<1, 64, 0, stream>>>((const uint32_t*)nmask, mflag, n);

    const int block = 256;
    const int grid  = (n + block - 1) / block;

    if (use_xbf) {
        const long total8 = (long)n * CIN / 8;
        const int cgrid = (int)((total8 + block - 1) / block);
        xcast_kernel<<<cgrid, block, 0, stream>>>(x, xbf, total8);
        conv1_kernel<1><<<grid, block, 0, stream>>>(xbf, W1, b1, nidx, nmask, mflag, hbuf, n);
    } else {
        conv1_kernel<0><<<grid, block, 0, stream>>>(x, W1, b1, nidx, nmask, mflag, hbuf, n);
    }
    conv2_kernel<<<grid, block, 0, stream>>>(x, W2, b2, Wp, bp, nidx, nmask, mflag, hbuf, (float*)d_out, n);
}